// Round 2
// baseline (2990.175 us; speedup 1.0000x reference)
//
#include <hip/hip_runtime.h>

// GCN 2-layer: out = A_hat * relu(A_hat * X * W1 + b1) * W2 + b2
// with A_hat = D^-1/2 (A + I) D^-1/2 (PyG GCNConv, flow row->col).
// Restructuring: out[c] = dinv[c] * sum_{e: col=c} (h[row_e]*dinv[row_e]) + b
// -> pre-scale rows, plain scatter-add, post-scale. Self-loop handled by
// initializing the agg buffer with the pre-scaled h (d2d copy).
// NOTE: harness delivers integer inputs as int32 (NOT the reference's int64).

__global__ __launch_bounds__(256) void k_zero(float* __restrict__ p, int n) {
    int i = blockIdx.x * 256 + threadIdx.x;
    if (i < n) p[i] = 0.0f;
}

__global__ __launch_bounds__(256) void k_deg(const int* __restrict__ col,
                                             float* __restrict__ deg, int E) {
    int i = blockIdx.x * 256 + threadIdx.x;
    if (i < E) atomicAdd(&deg[col[i]], 1.0f);
}

__global__ __launch_bounds__(256) void k_dinv(const float* __restrict__ deg,
                                              float* __restrict__ dinv, int N) {
    int i = blockIdx.x * 256 + threadIdx.x;
    if (i < N) dinv[i] = rsqrtf(deg[i] + 1.0f);  // +1 = self loop; always > 0
}

// out[i][c] = (sum_k X[i][k] * W[k][c]) * dinv[i],  c in [0,64). K = 128 or 64.
// One thread per row, 64 fp32 accumulators, W staged in LDS (<=32 KB).
__global__ __launch_bounds__(256) void k_gemm_rowscale(
    const float* __restrict__ X, const float* __restrict__ W,
    const float* __restrict__ dinv, float* __restrict__ out, int N, int K) {
    __shared__ float w_lds[128 * 64];
    int tid = threadIdx.x;
    int nv4 = K * 16;  // float4 count of W
    for (int i = tid; i < nv4; i += 256)
        ((float4*)w_lds)[i] = ((const float4*)W)[i];
    __syncthreads();
    int row = blockIdx.x * 256 + tid;
    if (row >= N) return;

    float acc[64];
#pragma unroll
    for (int c = 0; c < 64; ++c) acc[c] = 0.f;

    const float4* xr = (const float4*)(X + (size_t)row * K);
    int K4 = K >> 2;
    for (int k4 = 0; k4 < K4; ++k4) {
        float4 xv = xr[k4];
        const float* wk = w_lds + (k4 << 8);  // k4*4 rows of W, 64 wide
#pragma unroll
        for (int kk = 0; kk < 4; ++kk) {
            float xk = kk == 0 ? xv.x : kk == 1 ? xv.y : kk == 2 ? xv.z : xv.w;
            const float4* wrow = (const float4*)(wk + kk * 64);
#pragma unroll
            for (int c4 = 0; c4 < 16; ++c4) {
                float4 w = wrow[c4];
                acc[c4 * 4 + 0] = fmaf(xk, w.x, acc[c4 * 4 + 0]);
                acc[c4 * 4 + 1] = fmaf(xk, w.y, acc[c4 * 4 + 1]);
                acc[c4 * 4 + 2] = fmaf(xk, w.z, acc[c4 * 4 + 2]);
                acc[c4 * 4 + 3] = fmaf(xk, w.w, acc[c4 * 4 + 3]);
            }
        }
    }
    float s = dinv[row];
    float4* o = (float4*)(out + (size_t)row * 64);
#pragma unroll
    for (int c4 = 0; c4 < 16; ++c4) {
        float4 v;
        v.x = acc[c4 * 4 + 0] * s;
        v.y = acc[c4 * 4 + 1] * s;
        v.z = acc[c4 * 4 + 2] * s;
        v.w = acc[c4 * 4 + 3] * s;
        o[c4] = v;
    }
}

// One edge per 16-lane group; lane l handles channels [4l, 4l+4).
// dst must be pre-initialized with src (covers the self loop).
__global__ __launch_bounds__(256) void k_aggregate(
    const int* __restrict__ row, const int* __restrict__ col,
    const float* __restrict__ src, float* __restrict__ dst, int E) {
    long long gid = (long long)blockIdx.x * 256 + threadIdx.x;
    int e = (int)(gid >> 4);
    if (e >= E) return;
    int l = (int)(gid & 15);
    int r = row[e];
    int c = col[e];
    float4 v = ((const float4*)src)[(size_t)r * 16 + l];
    float* d = dst + (size_t)c * 64 + (size_t)l * 4;
    atomicAdd(d + 0, v.x);
    atomicAdd(d + 1, v.y);
    atomicAdd(d + 2, v.z);
    atomicAdd(d + 3, v.w);
}

// out[i][c] = agg[i][c] * dinv[i] + bias[c], optional relu.
__global__ __launch_bounds__(256) void k_postproc(
    const float* __restrict__ agg, const float* __restrict__ dinv,
    const float* __restrict__ bias, float* __restrict__ out, int N, int do_relu) {
    int idx = blockIdx.x * 256 + threadIdx.x;
    if (idx >= N * 16) return;
    int i = idx >> 4, l = idx & 15;
    float s = dinv[i];
    float4 v = ((const float4*)agg)[idx];
    float4 b = ((const float4*)bias)[l];
    v.x = v.x * s + b.x;
    v.y = v.y * s + b.y;
    v.z = v.z * s + b.z;
    v.w = v.w * s + b.w;
    if (do_relu) {
        v.x = fmaxf(v.x, 0.f);
        v.y = fmaxf(v.y, 0.f);
        v.z = fmaxf(v.z, 0.f);
        v.w = fmaxf(v.w, 0.f);
    }
    ((float4*)out)[idx] = v;
}

extern "C" void kernel_launch(void* const* d_in, const int* in_sizes, int n_in,
                              void* d_out, int out_size, void* d_ws, size_t ws_size,
                              hipStream_t stream) {
    const float* x = (const float*)d_in[0];
    const int* ei = (const int*)d_in[1];  // int32 per harness contract, [2, E]
    const float* W1 = (const float*)d_in[2];
    const float* b1 = (const float*)d_in[3];
    const float* W2 = (const float*)d_in[4];
    const float* b2 = (const float*)d_in[5];

    int N = in_sizes[0] / 128;  // 100000
    int E = in_sizes[1] / 2;    // 1600000
    const int* row = ei;
    const int* col = ei + E;

    char* ws = (char*)d_ws;
    float* deg = (float*)ws;                  // N floats @ 0
    float* dinv = (float*)(ws + (1 << 19));   // N floats @ 512 KB
    float* A = (float*)(ws + (1 << 20));      // N*64 floats @ 1 MB
    float* OUT = (float*)d_out;               // N*64 floats (used as 2nd buffer)
    size_t bigbytes = (size_t)N * 64 * sizeof(float);

    // Degree (in-degree at col) and dinv = rsqrt(deg + 1).
    k_zero<<<(N + 255) / 256, 256, 0, stream>>>(deg, N);
    k_deg<<<(E + 255) / 256, 256, 0, stream>>>(col, deg, E);
    k_dinv<<<(N + 255) / 256, 256, 0, stream>>>(deg, dinv, N);

    long long tot = (long long)E * 16;
    int agg_blocks = (int)((tot + 255) / 256);
    int pp_blocks = (N * 16 + 255) / 256;

    // Layer 1: h_scaled = (X@W1)*dinv -> A; agg into OUT (init = A, self loop);
    // h2 = relu(OUT*dinv + b1) -> A.
    k_gemm_rowscale<<<(N + 255) / 256, 256, 0, stream>>>(x, W1, dinv, A, N, 128);
    hipMemcpyAsync(OUT, A, bigbytes, hipMemcpyDeviceToDevice, stream);
    k_aggregate<<<agg_blocks, 256, 0, stream>>>(row, col, A, OUT, E);
    k_postproc<<<pp_blocks, 256, 0, stream>>>(OUT, dinv, b1, A, N, 1);

    // Layer 2: g_scaled = (A@W2)*dinv -> OUT; agg into A (init = OUT);
    // out = A*dinv + b2 -> d_out.
    k_gemm_rowscale<<<(N + 255) / 256, 256, 0, stream>>>(A, W2, dinv, OUT, N, 64);
    hipMemcpyAsync(A, OUT, bigbytes, hipMemcpyDeviceToDevice, stream);
    k_aggregate<<<agg_blocks, 256, 0, stream>>>(row, col, OUT, A, E);
    k_postproc<<<pp_blocks, 256, 0, stream>>>(A, dinv, b2, OUT, N, 0);
}

// Round 3
// 492.631 us; speedup vs baseline: 6.0698x; 6.0698x over previous
//
#include <hip/hip_runtime.h>

// GCN 2-layer, CSR-gather formulation (no fp32 atomics in the hot path).
//   out[c] = dinv[c] * ( h_s[c] + sum_{e: col=c} h_s[row_e] ) + b,  h_s = (X@W)*dinv
// CSR (col-sorted incoming-edge lists) is built once per launch and reused by
// both layers. Self-loop = accumulator init with h_s[c]. Postproc fused into
// the gather. Harness delivers integer inputs as int32.

__global__ __launch_bounds__(256) void k_zero_i(int* __restrict__ p, int n) {
    int i = blockIdx.x * 256 + threadIdx.x;
    if (i < n) p[i] = 0;
}

__global__ __launch_bounds__(256) void k_count(const int* __restrict__ col,
                                               int* __restrict__ cnt, int E) {
    int i = blockIdx.x * 256 + threadIdx.x;
    if (i < E) atomicAdd(&cnt[col[i]], 1);
}

// Per-block exclusive scan of cnt -> offsets (partial), block totals -> bsum.
__global__ __launch_bounds__(256) void k_scan_block(const int* __restrict__ cnt,
                                                    int* __restrict__ offsets,
                                                    int* __restrict__ bsum, int N) {
    __shared__ int s[256];
    int t = threadIdx.x;
    int i = blockIdx.x * 256 + t;
    int v = (i < N) ? cnt[i] : 0;
    s[t] = v;
    __syncthreads();
#pragma unroll
    for (int d = 1; d < 256; d <<= 1) {
        int x = (t >= d) ? s[t - d] : 0;
        __syncthreads();
        if (t >= d) s[t] += x;
        __syncthreads();
    }
    if (i < N) offsets[i] = s[t] - v;  // exclusive within block
    if (t == 255) bsum[blockIdx.x] = s[255];
}

// Single block: exclusive scan of up to 512 block sums, in place.
__global__ __launch_bounds__(512) void k_scan_tot(int* __restrict__ bsum, int nb) {
    __shared__ int s[512];
    int t = threadIdx.x;
    int v = (t < nb) ? bsum[t] : 0;
    s[t] = v;
    __syncthreads();
#pragma unroll
    for (int d = 1; d < 512; d <<= 1) {
        int x = (t >= d) ? s[t - d] : 0;
        __syncthreads();
        if (t >= d) s[t] += x;
        __syncthreads();
    }
    if (t < nb) bsum[t] = s[t] - v;  // exclusive
}

// Finalize: offsets += block offset; dinv = rsqrt(cnt+1); cursor init = offset.
// cursor may alias cnt (cnt is read before the aliased write).
__global__ __launch_bounds__(256) void k_finish(int* __restrict__ cnt,
                                                int* __restrict__ offsets,
                                                const int* __restrict__ bsum,
                                                int* __restrict__ cursor,
                                                float* __restrict__ dinv,
                                                int N, int E) {
    int i = blockIdx.x * 256 + threadIdx.x;
    if (i >= N) return;
    int c = cnt[i];
    dinv[i] = rsqrtf((float)c + 1.0f);  // +1 self loop; always > 0
    int off = offsets[i] + bsum[i >> 8];
    offsets[i] = off;
    cursor[i] = off;
    if (i == 0) offsets[N] = E;
}

// Scatter row indices into col-sorted edge array.
__global__ __launch_bounds__(256) void k_fill(const int* __restrict__ row,
                                              const int* __restrict__ col,
                                              int* __restrict__ cursor,
                                              int* __restrict__ eros, int E) {
    int i = blockIdx.x * 256 + threadIdx.x;
    if (i >= E) return;
    int p = atomicAdd(&cursor[col[i]], 1);
    eros[p] = row[i];
}

// out[i][c] = (sum_k X[i][k] * W[k][c]) * dinv[i],  c in [0,64). K = 128 or 64.
// One thread per row, 64 fp32 accumulators, W staged in LDS (<=32 KB).
__global__ __launch_bounds__(256) void k_gemm_rowscale(
    const float* __restrict__ X, const float* __restrict__ W,
    const float* __restrict__ dinv, float* __restrict__ out, int N, int K) {
    __shared__ float w_lds[128 * 64];
    int tid = threadIdx.x;
    int nv4 = K * 16;
    for (int i = tid; i < nv4; i += 256)
        ((float4*)w_lds)[i] = ((const float4*)W)[i];
    __syncthreads();
    int row = blockIdx.x * 256 + tid;
    if (row >= N) return;

    float acc[64];
#pragma unroll
    for (int c = 0; c < 64; ++c) acc[c] = 0.f;

    const float4* xr = (const float4*)(X + (size_t)row * K);
    int K4 = K >> 2;
    for (int k4 = 0; k4 < K4; ++k4) {
        float4 xv = xr[k4];
        const float* wk = w_lds + (k4 << 8);
#pragma unroll
        for (int kk = 0; kk < 4; ++kk) {
            float xk = kk == 0 ? xv.x : kk == 1 ? xv.y : kk == 2 ? xv.z : xv.w;
            const float4* wrow = (const float4*)(wk + kk * 64);
#pragma unroll
            for (int c4 = 0; c4 < 16; ++c4) {
                float4 w = wrow[c4];
                acc[c4 * 4 + 0] = fmaf(xk, w.x, acc[c4 * 4 + 0]);
                acc[c4 * 4 + 1] = fmaf(xk, w.y, acc[c4 * 4 + 1]);
                acc[c4 * 4 + 2] = fmaf(xk, w.z, acc[c4 * 4 + 2]);
                acc[c4 * 4 + 3] = fmaf(xk, w.w, acc[c4 * 4 + 3]);
            }
        }
    }
    float s = dinv[row];
    float4* o = (float4*)(out + (size_t)row * 64);
#pragma unroll
    for (int c4 = 0; c4 < 16; ++c4) {
        float4 v;
        v.x = acc[c4 * 4 + 0] * s;
        v.y = acc[c4 * 4 + 1] * s;
        v.z = acc[c4 * 4 + 2] * s;
        v.w = acc[c4 * 4 + 3] * s;
        o[c4] = v;
    }
}

// Gather-aggregate + fused postproc. One 16-lane group per node; lane l owns
// channels [4l, 4l+4). acc init = src[node] (self loop). No atomics.
__global__ __launch_bounds__(256) void k_gather(
    const float* __restrict__ src, const int* __restrict__ offsets,
    const int* __restrict__ eros, const float* __restrict__ dinv,
    const float* __restrict__ bias, float* __restrict__ dst, int N, int do_relu) {
    int idx = blockIdx.x * 256 + threadIdx.x;
    int node = idx >> 4;
    if (node >= N) return;
    int l = idx & 15;

    const float4* s4 = (const float4*)src;
    float4 acc = s4[(size_t)node * 16 + l];  // self loop
    int e = offsets[node], eend = offsets[node + 1];
    for (; e < eend; ++e) {
        int r = eros[e];
        float4 v = s4[(size_t)r * 16 + l];
        acc.x += v.x; acc.y += v.y; acc.z += v.z; acc.w += v.w;
    }
    float sc = dinv[node];
    float4 b = ((const float4*)bias)[l];
    acc.x = acc.x * sc + b.x;
    acc.y = acc.y * sc + b.y;
    acc.z = acc.z * sc + b.z;
    acc.w = acc.w * sc + b.w;
    if (do_relu) {
        acc.x = fmaxf(acc.x, 0.f);
        acc.y = fmaxf(acc.y, 0.f);
        acc.z = fmaxf(acc.z, 0.f);
        acc.w = fmaxf(acc.w, 0.f);
    }
    ((float4*)dst)[(size_t)node * 16 + l] = acc;
}

extern "C" void kernel_launch(void* const* d_in, const int* in_sizes, int n_in,
                              void* d_out, int out_size, void* d_ws, size_t ws_size,
                              hipStream_t stream) {
    const float* x = (const float*)d_in[0];
    const int* ei = (const int*)d_in[1];  // int32 per harness contract, [2, E]
    const float* W1 = (const float*)d_in[2];
    const float* b1 = (const float*)d_in[3];
    const float* W2 = (const float*)d_in[4];
    const float* b2 = (const float*)d_in[5];

    int N = in_sizes[0] / 128;  // 100000
    int E = in_sizes[1] / 2;    // 1600000
    const int* row = ei;
    const int* col = ei + E;

    char* ws = (char*)d_ws;
    int* cnt = (int*)ws;                        // N ints @ 0 (reused as cursor)
    int* offsets = (int*)(ws + (1 << 19));      // N+1 ints @ 512 KB
    float* dinv = (float*)(ws + (1 << 20));     // N floats @ 1 MB
    int* bsum = (int*)(ws + (3 << 19));         // <=512 ints @ 1.5 MB
    int* eros = (int*)(ws + (1 << 21));         // E ints @ 2 MB (6.4 MB)
    float* A = (float*)(ws + (9 << 20));        // N*64 floats @ 9 MB (25.6 MB)
    float* OUT = (float*)d_out;                 // N*64 floats, used as 2nd buffer

    int nblk = (N + 255) / 256;  // 391 (<=512 required by k_scan_tot)
    int eblk = (E + 255) / 256;

    // --- CSR build (once, shared by both layers) ---
    k_zero_i<<<nblk, 256, 0, stream>>>(cnt, N);
    k_count<<<eblk, 256, 0, stream>>>(col, cnt, E);
    k_scan_block<<<nblk, 256, 0, stream>>>(cnt, offsets, bsum, N);
    k_scan_tot<<<1, 512, 0, stream>>>(bsum, nblk);
    k_finish<<<nblk, 256, 0, stream>>>(cnt, offsets, bsum, cnt /*cursor*/, dinv, N, E);
    k_fill<<<eblk, 256, 0, stream>>>(row, col, cnt /*cursor*/, eros, E);

    int gblk = (N * 16 + 255) / 256;

    // Layer 1: A = (X@W1)*dinv; OUT = relu(gather(A)*dinv + b1)
    k_gemm_rowscale<<<nblk, 256, 0, stream>>>(x, W1, dinv, A, N, 128);
    k_gather<<<gblk, 256, 0, stream>>>(A, offsets, eros, dinv, b1, OUT, N, 1);

    // Layer 2: A = (OUT@W2)*dinv; d_out = gather(A)*dinv + b2
    k_gemm_rowscale<<<nblk, 256, 0, stream>>>(OUT, W2, dinv, A, N, 64);
    k_gather<<<gblk, 256, 0, stream>>>(A, offsets, eros, dinv, b2, OUT, N, 0);
}